// Round 1
// 1410.431 us; speedup vs baseline: 1.0373x; 1.0373x over previous
//
#include <hip/hip_runtime.h>

typedef _Float16 half_t;
typedef __attribute__((ext_vector_type(8))) _Float16 half8;
typedef __attribute__((ext_vector_type(4))) _Float16 half4;
typedef __attribute__((ext_vector_type(4))) float f32x4;

#define GLD(gp, lp) \
  __builtin_amdgcn_global_load_lds((const __attribute__((address_space(1))) void*)(gp), \
                                   (__attribute__((address_space(3))) void*)(lp), 16, 0, 0)

// ---------------------------------------------------------------- fp32 -> fp16
__global__ __launch_bounds__(256) void cvt_kernel(const float* __restrict__ src,
                                                  half_t* __restrict__ dst, int n4) {
  int i = blockIdx.x * 256 + threadIdx.x;
  int stride = gridDim.x * 256;
  for (; i < n4; i += stride) {
    f32x4 v = *((const f32x4*)src + i);
    half4 o;
    o[0] = (half_t)v[0]; o[1] = (half_t)v[1];
    o[2] = (half_t)v[2]; o[3] = (half_t)v[3];
    *((half4*)dst + i) = o;
  }
}

// ---------------------------------------------------------------- fused QKV GEMM
// C[M=147456, N=512] = X @ W^T (+bias), then for q/k: L2-normalize over Dh=32,
// q additionally scaled by exp(min(logit_scale[h], log(100))).
// m97 structure, now with:
//  - double-buffered LDS + prefetch (STAGE t+1 before computing t; one barrier/iter)
//    so the compiler's vmcnt(0)-before-barrier drains loads issued a full compute
//    phase earlier instead of 0 cycles earlier.
//  - bijective XCD swizzle so the 12 n-sub blocks of one m-tile share an XCD L2
//    (kills the 4x A-panel over-fetch: 596 MB -> ~compulsory).
__global__ __launch_bounds__(256) void qkv_gemm(
    const half_t* __restrict__ xh,
    const half_t* __restrict__ wq, const half_t* __restrict__ wk, const half_t* __restrict__ wv,
    const float* __restrict__ bq, const float* __restrict__ bk, const float* __restrict__ bv,
    const float* __restrict__ logit_scale,
    half_t* __restrict__ qout, half_t* __restrict__ kout, half_t* __restrict__ vout) {
  __shared__ alignas(16) half_t As[2 * 128 * 32];
  __shared__ alignas(16) half_t Bs[2 * 128 * 32];

  // XCD-aware bijective swizzle: nwg = 13824 = 8 * 1728.
  int bid = blockIdx.x;
  bid = (bid & 7) * 1728 + (bid >> 3);

  int mtile = bid / 12, nsub = bid % 12;
  int mat = nsub >> 2;                 // 0=q 1=k 2=v
  int n0 = (nsub & 3) << 7;
  long m0 = (long)mtile << 7;
  const half_t* W    = (mat == 0) ? wq : (mat == 1) ? wk : wv;
  const float*  bias = (mat == 0) ? bq : (mat == 1) ? bk : bv;
  half_t*       out  = (mat == 0) ? qout : (mat == 1) ? kout : vout;

  int tid = threadIdx.x, lane = tid & 63, wid = tid >> 6;
  int quad = lane >> 4, c = lane & 15;
  int wm = (wid & 1) << 6, wn = (wid >> 1) << 6;

  f32x4 acc[4][4] = {};

  const half_t* Abase = xh + m0 * 512;
  const half_t* Bbase = W + (long)n0 * 512;
  int r_lo = lane >> 2;            // 0..15 (row within 16-row chunk)
  int cp   = (lane & 3) << 3;      // half offset within row

#define STAGE_T(buf, kkv)                                                        \
  {                                                                              \
    _Pragma("unroll")                                                            \
    for (int ci = 0; ci < 2; ci++) {                                             \
      int ch = wid + ci * 4;                                                     \
      int row = (ch << 4) + r_lo;                                                \
      GLD(Abase + (long)row * 512 + (kkv) + cp, As + (buf) * 4096 + (ch << 9));  \
      GLD(Bbase + (long)row * 512 + (kkv) + cp, Bs + (buf) * 4096 + (ch << 9));  \
    }                                                                            \
  }

  // prologue: stage K-tile 0 into buffer 0
  STAGE_T(0, 0);
  int cur = 0;

  for (int kk = 0; kk < 512; kk += 32) {
    // barrier: (a) vmcnt(0) drain -> buf[cur] staged data has landed,
    //          (b) all waves done reading buf[cur^1] from last iter.
    __syncthreads();
    if (kk < 480) STAGE_T(cur ^ 1, kk + 32);   // prefetch next tile; hides under MFMA below

    const half_t* Ab = As + cur * 4096;
    const half_t* Bb = Bs + cur * 4096;
    half8 af[4], bf[4];
#pragma unroll
    for (int mi = 0; mi < 4; mi++)
      af[mi] = *(const half8*)(Ab + ((wm + (mi << 4) + c) << 5) + (quad << 3));
#pragma unroll
    for (int ni = 0; ni < 4; ni++)
      bf[ni] = *(const half8*)(Bb + ((wn + (ni << 4) + c) << 5) + (quad << 3));
#pragma unroll
    for (int mi = 0; mi < 4; mi++)
#pragma unroll
      for (int ni = 0; ni < 4; ni++)
        acc[mi][ni] = __builtin_amdgcn_mfma_f32_16x16x32_f16(af[mi], bf[ni], acc[mi][ni], 0, 0, 0);
    cur ^= 1;
  }

  // epilogue: bias, L2-norm over the head's 32 cols (2 adjacent 16-col tiles),
  // fold logit scale into q, store fp16 in (M, C) layout.
#pragma unroll
  for (int mi = 0; mi < 4; mi++) {
#pragma unroll
    for (int hh = 0; hh < 2; hh++) {
      f32x4 a0 = acc[mi][2 * hh], a1 = acc[mi][2 * hh + 1];
      int col0 = n0 + wn + (hh << 5) + c;
      float b0 = bias[col0], b1 = bias[col0 + 16];
#pragma unroll
      for (int r = 0; r < 4; r++) { a0[r] += b0; a1[r] += b1; }
      if (mat != 2) {
        float sc = 1.f;
        if (mat == 0) {
          int hidx = (n0 + wn + (hh << 5)) >> 5;
          sc = __expf(fminf(logit_scale[hidx], 4.60517018598809f));
        }
        float ss[4];
#pragma unroll
        for (int r = 0; r < 4; r++) ss[r] = a0[r] * a0[r] + a1[r] * a1[r];
#pragma unroll
        for (int d = 1; d < 16; d <<= 1)
#pragma unroll
          for (int r = 0; r < 4; r++) ss[r] += __shfl_xor(ss[r], d);
#pragma unroll
        for (int r = 0; r < 4; r++) {
          float inv = sc / fmaxf(sqrtf(ss[r]), 1e-12f);
          a0[r] *= inv; a1[r] *= inv;
        }
      }
      long grow = m0 + wm + (mi << 4) + (quad << 2);
#pragma unroll
      for (int r = 0; r < 4; r++) {
        out[(grow + r) * 512 + col0]      = (half_t)a0[r];
        out[(grow + r) * 512 + col0 + 16] = (half_t)a1[r];
      }
    }
  }
#undef STAGE_T
}

// ---------------------------------------------------------------- attention
// One block per (b,h); 9 waves, wave w owns q-rows [16w,16w+16).
// S = q·k^T via direct-global MFMA frags (K=Dh=32 exactly one 16x16x32 step),
// +mask, softmax via 16-lane shuffles, P->LDS (stride 176), PV with K padded to 160.
__global__ __launch_bounds__(576) void attn_kernel(
    const half_t* __restrict__ qh, const half_t* __restrict__ kh, const half_t* __restrict__ vh,
    const float* __restrict__ mask, half_t* __restrict__ Oh) {
  __shared__ alignas(16) half_t Pl[144 * 176];
  __shared__ alignas(16) half_t Vt[32 * 176];
  int b = blockIdx.x, h = blockIdx.y;
  int win = b & 63;
  int tid = threadIdx.x, lane = tid & 63, w = tid >> 6;
  int quad = lane >> 4, c = lane & 15;

  // stage V transposed: Vt[d][m], zero-pad m=144..159
  const half_t* vbase = vh + ((long)b * 144) * 512 + h * 32;
#pragma unroll
  for (int t = 0; t < 8; t++) {
    int i = tid + t * 576;
    int l = i >> 5, d = i & 31;
    Vt[d * 176 + l] = vbase[(long)l * 512 + d];
  }
  if (tid < 512) { int d = tid >> 4, l = 144 + (tid & 15); Vt[d * 176 + l] = (half_t)0.f; }
  __syncthreads();

  const half_t* qbase = qh + ((long)b * 144) * 512 + h * 32;
  const half_t* kbase = kh + ((long)b * 144) * 512 + h * 32;
  half8 aq = *(const half8*)(qbase + (long)(w * 16 + c) * 512 + quad * 8);
  f32x4 s[9];
#pragma unroll
  for (int nt = 0; nt < 9; nt++) {
    half8 bk = *(const half8*)(kbase + (long)(nt * 16 + c) * 512 + quad * 8);
    f32x4 z = {0.f, 0.f, 0.f, 0.f};
    s[nt] = __builtin_amdgcn_mfma_f32_16x16x32_f16(aq, bk, z, 0, 0, 0);
  }

  const float* mbase = mask + ((long)win * 144 + w * 16 + quad * 4) * 144 + c;
  float mx[4] = {-1e30f, -1e30f, -1e30f, -1e30f};
#pragma unroll
  for (int nt = 0; nt < 9; nt++)
#pragma unroll
    for (int r = 0; r < 4; r++) {
      s[nt][r] += mbase[r * 144 + nt * 16];
      mx[r] = fmaxf(mx[r], s[nt][r]);
    }
#pragma unroll
  for (int d = 1; d < 16; d <<= 1)
#pragma unroll
    for (int r = 0; r < 4; r++) mx[r] = fmaxf(mx[r], __shfl_xor(mx[r], d));

  float sum[4] = {0.f, 0.f, 0.f, 0.f};
#pragma unroll
  for (int nt = 0; nt < 9; nt++)
#pragma unroll
    for (int r = 0; r < 4; r++) {
      float p = __expf(s[nt][r] - mx[r]);
      s[nt][r] = p; sum[r] += p;
    }
#pragma unroll
  for (int d = 1; d < 16; d <<= 1)
#pragma unroll
    for (int r = 0; r < 4; r++) sum[r] += __shfl_xor(sum[r], d);

  int prow = w * 16 + quad * 4;
#pragma unroll
  for (int r = 0; r < 4; r++) {
#pragma unroll
    for (int nt = 0; nt < 9; nt++)
      Pl[(prow + r) * 176 + nt * 16 + c] = (half_t)s[nt][r];
    Pl[(prow + r) * 176 + 144 + c] = (half_t)0.f;   // zero-pad K cols 144..159
  }

  // PV: wave reads only its own P strip (no barrier needed; Vt was barriered)
  f32x4 o0 = {0.f, 0.f, 0.f, 0.f}, o1 = {0.f, 0.f, 0.f, 0.f};
#pragma unroll
  for (int ks = 0; ks < 5; ks++) {
    half8 ap = *(const half8*)(Pl + (w * 16 + c) * 176 + ks * 32 + quad * 8);
    half8 b0 = *(const half8*)(Vt + c * 176 + ks * 32 + quad * 8);
    half8 b1 = *(const half8*)(Vt + (16 + c) * 176 + ks * 32 + quad * 8);
    o0 = __builtin_amdgcn_mfma_f32_16x16x32_f16(ap, b0, o0, 0, 0, 0);
    o1 = __builtin_amdgcn_mfma_f32_16x16x32_f16(ap, b1, o1, 0, 0, 0);
  }

  half_t* obase = Oh + ((long)b * 144) * 512 + h * 32;
#pragma unroll
  for (int r = 0; r < 4; r++) {
    float rs = 1.f / sum[r];
    obase[(long)(prow + r) * 512 + c]      = (half_t)(o0[r] * rs);
    obase[(long)(prow + r) * 512 + 16 + c] = (half_t)(o1[r] * rs);
  }
}

// ---------------------------------------------------------------- output GEMM
// Same dbuf-prefetch 2-phase + XCD swizzle as qkv_gemm. nwg = 4608 = 8*576.
__global__ __launch_bounds__(256) void out_gemm(
    const half_t* __restrict__ Ah, const half_t* __restrict__ W,
    const float* __restrict__ bias, float* __restrict__ y) {
  __shared__ alignas(16) half_t As[2 * 128 * 32];
  __shared__ alignas(16) half_t Bs[2 * 128 * 32];

  int bid = blockIdx.x;
  bid = (bid & 7) * 576 + (bid >> 3);

  long m0 = (long)(bid >> 2) << 7;
  int n0 = (bid & 3) << 7;
  int tid = threadIdx.x, lane = tid & 63, wid = tid >> 6;
  int quad = lane >> 4, c = lane & 15;
  int wm = (wid & 1) << 6, wn = (wid >> 1) << 6;
  f32x4 acc[4][4] = {};
  const half_t* Abase = Ah + m0 * 512;
  const half_t* Bbase = W + (long)n0 * 512;
  int r_lo = lane >> 2, cp = (lane & 3) << 3;

#define STAGE_T(buf, kkv)                                                        \
  {                                                                              \
    _Pragma("unroll")                                                            \
    for (int ci = 0; ci < 2; ci++) {                                             \
      int ch = wid + ci * 4;                                                     \
      int row = (ch << 4) + r_lo;                                                \
      GLD(Abase + (long)row * 512 + (kkv) + cp, As + (buf) * 4096 + (ch << 9));  \
      GLD(Bbase + (long)row * 512 + (kkv) + cp, Bs + (buf) * 4096 + (ch << 9));  \
    }                                                                            \
  }

  STAGE_T(0, 0);
  int cur = 0;

  for (int kk = 0; kk < 512; kk += 32) {
    __syncthreads();
    if (kk < 480) STAGE_T(cur ^ 1, kk + 32);

    const half_t* Ab = As + cur * 4096;
    const half_t* Bb = Bs + cur * 4096;
    half8 af[4], bf[4];
#pragma unroll
    for (int mi = 0; mi < 4; mi++)
      af[mi] = *(const half8*)(Ab + ((wm + (mi << 4) + c) << 5) + (quad << 3));
#pragma unroll
    for (int ni = 0; ni < 4; ni++)
      bf[ni] = *(const half8*)(Bb + ((wn + (ni << 4) + c) << 5) + (quad << 3));
#pragma unroll
    for (int mi = 0; mi < 4; mi++)
#pragma unroll
      for (int ni = 0; ni < 4; ni++)
        acc[mi][ni] = __builtin_amdgcn_mfma_f32_16x16x32_f16(af[mi], bf[ni], acc[mi][ni], 0, 0, 0);
    cur ^= 1;
  }

#pragma unroll
  for (int mi = 0; mi < 4; mi++)
#pragma unroll
    for (int ni = 0; ni < 4; ni++) {
      int col = n0 + wn + (ni << 4) + c;
      float bv_ = bias[col];
      long grow = m0 + wm + (mi << 4) + (quad << 2);
#pragma unroll
      for (int r = 0; r < 4; r++)
        y[(grow + r) * 512 + col] = acc[mi][ni][r] + bv_;
    }
#undef STAGE_T
}

// ---------------------------------------------------------------- launch
extern "C" void kernel_launch(void* const* d_in, const int* in_sizes, int n_in,
                              void* d_out, int out_size, void* d_ws, size_t ws_size,
                              hipStream_t stream) {
  const float* x    = (const float*)d_in[0];
  const float* mask = (const float*)d_in[1];
  const float* Wq   = (const float*)d_in[2];
  const float* bq   = (const float*)d_in[3];
  const float* Wk   = (const float*)d_in[4];
  const float* bk   = (const float*)d_in[5];
  const float* Wv   = (const float*)d_in[6];
  const float* bv   = (const float*)d_in[7];
  const float* Wp   = (const float*)d_in[8];
  const float* bp   = (const float*)d_in[9];
  const float* ls   = (const float*)d_in[10];

  const long MT = 147456L * 512;            // 75,497,472 elements
  half_t* xh  = (half_t*)d_ws;
  half_t* vh  = xh + MT;
  half_t* Oh  = vh + MT;
  half_t* wqh = Oh + MT;
  half_t* wkh = wqh + 262144;
  half_t* wvh = wkh + 262144;
  half_t* wph = wvh + 262144;
  half_t* qh  = (half_t*)d_out;             // q,k live in d_out (dead before final GEMM)
  half_t* kh  = qh + MT;
  float*  y   = (float*)d_out;

  cvt_kernel<<<73728, 256, 0, stream>>>(x, xh, (int)(MT / 4));
  cvt_kernel<<<256, 256, 0, stream>>>(Wq, wqh, 65536);
  cvt_kernel<<<256, 256, 0, stream>>>(Wk, wkh, 65536);
  cvt_kernel<<<256, 256, 0, stream>>>(Wv, wvh, 65536);
  cvt_kernel<<<256, 256, 0, stream>>>(Wp, wph, 65536);
  qkv_gemm<<<13824, 256, 0, stream>>>(xh, wqh, wkh, wvh, bq, bk, bv, ls, qh, kh, vh);
  attn_kernel<<<dim3(1024, 16), 576, 0, stream>>>(qh, kh, vh, mask, Oh);
  out_gemm<<<4608, 256, 0, stream>>>(Oh, wph, bp, y);
}